// Round 7
// baseline (77.097 us; speedup 1.0000x reference)
//
#include <hip/hip_runtime.h>
#include <stdint.h>

#define BATCH 2048
#define INF 1024
#define OUTF 1024
#define GRID_G 8
#define KTOT 9216   // INF + INF*GRID_G

#define BM 256
#define BN 256
#define BK 64
#define SK 8
#define KC (KTOT / SK)   // 1152
#define NKT (KC / BK)    // 18 (even, required by 2x-unrolled loop)
#define MTT (BATCH / BM) // 8
#define NTT (OUTF / BN)  // 4
#define CSLAB ((size_t)BATCH * OUTF)

typedef __attribute__((ext_vector_type(8))) short short8_t;
typedef __attribute__((ext_vector_type(4))) float f32x4_t;
typedef __attribute__((ext_vector_type(8))) unsigned short u16x8_t;

__device__ __forceinline__ unsigned short f2bf(float f) {
  unsigned int u = __float_as_uint(f);
  u += 0x7FFFu + ((u >> 16) & 1u);
  return (unsigned short)(u >> 16);
}

__device__ __forceinline__ void async16(void* lds, const void* g) {
  __builtin_amdgcn_global_load_lds(
      (const __attribute__((address_space(1))) void*)g,
      (__attribute__((address_space(3))) void*)lds, 16, 0, 0);
}

// Build W_cat[o][k]: k<1024 -> bf16(base_weight[o][k]); else bf16(coeff[o][k-1024])
__global__ __launch_bounds__(256) void build_w_kernel(
    const float* __restrict__ bw, const float* __restrict__ coeff,
    unsigned short* __restrict__ wc) {
  int id = blockIdx.x * 256 + threadIdx.x;  // one thread per 8 elements
  int row = id / (KTOT / 8);
  int k8 = id - row * (KTOT / 8);
  int k = k8 * 8;
  const float* src = (k < INF) ? (bw + (size_t)row * INF + k)
                               : (coeff + (size_t)row * (INF * GRID_G) + (k - INF));
  const float4* s4 = (const float4*)src;
  float4 a = s4[0], b = s4[1];
  u16x8_t v;
  v[0] = f2bf(a.x); v[1] = f2bf(a.y); v[2] = f2bf(a.z); v[3] = f2bf(a.w);
  v[4] = f2bf(b.x); v[5] = f2bf(b.y); v[6] = f2bf(b.z); v[7] = f2bf(b.w);
  *(u16x8_t*)(wc + (size_t)id * 8) = v;
}

// Build A_cat[b][k]: k<1024 -> bf16(x[b][k]); spline block: one-hot(idx)*bf16(0.1*w)
__global__ __launch_bounds__(256) void build_a_kernel(
    const float* __restrict__ x, const float* __restrict__ grid,
    unsigned short* __restrict__ ac) {
  __shared__ float sg[GRID_G + 1];
  if (threadIdx.x <= GRID_G) sg[threadIdx.x] = grid[threadIdx.x];
  __syncthreads();
  int id = blockIdx.x * 256 + threadIdx.x;  // one per (b,i)
  int b = id >> 10;
  int i = id & 1023;
  float xv = x[id];
  ac[(size_t)b * KTOT + i] = f2bf(xv);
  float xc = fminf(fmaxf(xv, -1.0f), 1.0f);
  int cnt = 0;
#pragma unroll
  for (int j = 0; j <= GRID_G; ++j) cnt += (xc >= sg[j]) ? 1 : 0;
  int idx = cnt - 1;
  idx = idx < 0 ? 0 : (idx > GRID_G - 1 ? GRID_G - 1 : idx);
  float left = sg[idx], right = sg[idx + 1];
  float denom = right - left;
  denom = (denom == 0.0f) ? 1.0f : denom;
  float w = (xc - left) / denom;
  unsigned short val = f2bf(0.1f * w);
  u16x8_t v;
#pragma unroll
  for (int g = 0; g < GRID_G; ++g) v[g] = (g == idx) ? val : (unsigned short)0;
  *(u16x8_t*)(ac + (size_t)b * KTOT + INF + (size_t)i * 8) = v;
}

// 256x256x(BK=64) split-K GEMM. 4 phases per K-tile pair-unrolled so that every
// LDS object is a DISTINCT, statically-named __shared__ array per (buf,ks) --
// this keeps the compiler's auto-inserted LDSDMA-alias waits at vmcnt(>=4)
// (no-ops behind our explicit vmcnt(4) gate) instead of the catastrophic
// vmcnt(0) full drain it must emit when a ds_read follows a same-object
// global_load_lds (the R4-R6 25%-MfmaUtil wall).
// Within each phase: ALL ds_reads -> stages -> MFMA (m201 order).
// Chunk-transposed block layout (R6): conflict-free ds_read_b128 (measured 0).
__global__ __launch_bounds__(512, 2) void gemm_kernel(
    const unsigned short* __restrict__ A, const unsigned short* __restrict__ W,
    unsigned short* __restrict__ P) {
  // 8 x 16 KB = 128 KB
  __shared__ unsigned short A0K0[256 * 32], A0K1[256 * 32];
  __shared__ unsigned short A1K0[256 * 32], A1K1[256 * 32];
  __shared__ unsigned short B0K0[256 * 32], B0K1[256 * 32];
  __shared__ unsigned short B1K0[256 * 32], B1K1[256 * 32];

  int bid = blockIdx.x;
  int sk = bid & 7;          // XCD affinity: one sk-slab per XCD
  int t0 = bid >> 3;         // 0..31
  int mt = t0 >> 2;          // 0..7
  int nt = t0 & 3;           // 0..3

  int tid = threadIdx.x;
  int wave = tid >> 6;
  int lane = tid & 63;
  int wr = wave >> 2, wc = wave & 3;   // 2x4 wave grid; per-wave C = 128x64
  int lr = lane & 15, lk = lane >> 4;
  // chunk-transposed per-lane read offset (elements) within a 512-elem block
  int rlo = lk * 128 + lr * 8;

  // staging source (chunk-transpose): lane l -> row wave*16+(l&15), chunk l>>4;
  // 2nd async16 (+4096 elem dest) covers rows 128..255 via +128*KTOT source
  int srow = (tid >> 6) * 16 + (tid & 15);
  int scol = ((tid >> 4) & 3) * 8;
  const unsigned short* gA  = A + (size_t)(mt * BM + srow) * KTOT + sk * KC + scol;
  const unsigned short* gA2 = gA + (size_t)128 * KTOT;
  const unsigned short* gB  = W + (size_t)(nt * BN + srow) * KTOT + sk * KC + scol;
  const unsigned short* gB2 = gB + (size_t)128 * KTOT;

  f32x4_t acc[2][4][4];
#pragma unroll
  for (int ch = 0; ch < 2; ++ch)
#pragma unroll
    for (int mf = 0; mf < 4; ++mf)
#pragma unroll
      for (int nf = 0; nf < 4; ++nf) acc[ch][mf][nf] = f32x4_t{0.f, 0.f, 0.f, 0.f};

#define GATE(pf_) { if (pf_) asm volatile("s_waitcnt vmcnt(4)" ::: "memory"); \
    else asm volatile("s_waitcnt vmcnt(0)" ::: "memory"); \
    __builtin_amdgcn_s_barrier(); \
    asm volatile("" ::: "memory"); }

// One phase: gate -> 12x ds_read_b128 (objects named statically) ->
// 4x global_load_lds prefetch (distinct objects) -> 32 MFMA under setprio.
#define PHASE(CB, NB, KS, tt, pf_) { \
    short8_t af0[4], af1[4], bfv[4]; \
    GATE(pf_) \
    _Pragma("unroll") for (int mf = 0; mf < 4; ++mf) \
      af0[mf] = *(const short8_t*)&A##CB##K##KS[(wr * 8 + mf) * 512 + rlo]; \
    _Pragma("unroll") for (int nf = 0; nf < 4; ++nf) \
      bfv[nf] = *(const short8_t*)&B##CB##K##KS[(wc * 4 + nf) * 512 + rlo]; \
    _Pragma("unroll") for (int mf = 0; mf < 4; ++mf) \
      af1[mf] = *(const short8_t*)&A##CB##K##KS[(wr * 8 + 4 + mf) * 512 + rlo]; \
    if (pf_) { \
      unsigned short* dA = &A##NB##K##KS[wave * 512]; \
      async16(dA, gA + (tt) * BK + (KS) * 32); \
      async16(dA + 4096, gA2 + (tt) * BK + (KS) * 32); \
      unsigned short* dB = &B##NB##K##KS[wave * 512]; \
      async16(dB, gB + (tt) * BK + (KS) * 32); \
      async16(dB + 4096, gB2 + (tt) * BK + (KS) * 32); \
    } \
    __builtin_amdgcn_s_setprio(1); \
    _Pragma("unroll") for (int mf = 0; mf < 4; ++mf) \
    _Pragma("unroll") for (int nf = 0; nf < 4; ++nf) \
      acc[0][mf][nf] = __builtin_amdgcn_mfma_f32_16x16x32_bf16( \
          af0[mf], bfv[nf], acc[0][mf][nf], 0, 0, 0); \
    _Pragma("unroll") for (int mf = 0; mf < 4; ++mf) \
    _Pragma("unroll") for (int nf = 0; nf < 4; ++nf) \
      acc[1][mf][nf] = __builtin_amdgcn_mfma_f32_16x16x32_bf16( \
          af1[mf], bfv[nf], acc[1][mf][nf], 0, 0, 0); \
    __builtin_amdgcn_s_setprio(0); \
}

  // prologue: tile 0 into buf 0 (ks0 pair first -> first gate's vmcnt(4) math)
  {
    unsigned short* dA = &A0K0[wave * 512];
    async16(dA, gA); async16(dA + 4096, gA2);
    unsigned short* dB = &B0K0[wave * 512];
    async16(dB, gB); async16(dB + 4096, gB2);
    unsigned short* dA1 = &A0K1[wave * 512];
    async16(dA1, gA + 32); async16(dA1 + 4096, gA2 + 32);
    unsigned short* dB1 = &B0K1[wave * 512];
    async16(dB1, gB + 32); async16(dB1 + 4096, gB2 + 32);
  }

  for (int t2 = 0; t2 < NKT; t2 += 2) {
    bool p1 = (t2 + 1) < NKT;   // stage tile t2+1 into buf1
    bool p2 = (t2 + 2) < NKT;   // stage tile t2+2 into buf0
    PHASE(0, 1, 0, t2 + 1, p1)
    PHASE(0, 1, 1, t2 + 1, p1)
    PHASE(1, 0, 0, t2 + 2, p2)
    PHASE(1, 0, 1, t2 + 2, p2)
  }

  // epilogue: C/D col=lane&15 (n), row=(lane>>4)*4+reg (m); private bf16 slab
  unsigned short* slab = P + (size_t)sk * CSLAB;
#pragma unroll
  for (int ch = 0; ch < 2; ++ch)
#pragma unroll
    for (int mf = 0; mf < 4; ++mf)
#pragma unroll
      for (int nf = 0; nf < 4; ++nf) {
        int col = nt * BN + wc * 64 + nf * 16 + lr;
        int rowb = mt * BM + wr * 128 + ch * 64 + mf * 16 + lk * 4;
#pragma unroll
        for (int r = 0; r < 4; ++r)
          slab[(size_t)(rowb + r) * OUTF + col] = f2bf(acc[ch][mf][nf][r]);
      }
}

// out[e] = sum_sk P[sk][e]; 8 elements/thread, fully overwrites d_out.
__global__ __launch_bounds__(256) void reduce_kernel(
    const unsigned short* __restrict__ P, float* __restrict__ out) {
  size_t base = ((size_t)blockIdx.x * 256 + threadIdx.x) * 8;
  float s[8];
#pragma unroll
  for (int j = 0; j < 8; ++j) s[j] = 0.0f;
#pragma unroll
  for (int k = 0; k < SK; ++k) {
    u16x8_t v = *(const u16x8_t*)(P + (size_t)k * CSLAB + base);
#pragma unroll
    for (int j = 0; j < 8; ++j)
      s[j] += __uint_as_float((unsigned int)v[j] << 16);
  }
  float4 lo = {s[0], s[1], s[2], s[3]};
  float4 hi = {s[4], s[5], s[6], s[7]};
  *(float4*)(out + base) = lo;
  *(float4*)(out + base + 4) = hi;
}

extern "C" void kernel_launch(void* const* d_in, const int* in_sizes, int n_in,
                              void* d_out, int out_size, void* d_ws, size_t ws_size,
                              hipStream_t stream) {
  const float* x = (const float*)d_in[0];
  const float* bw = (const float*)d_in[1];
  const float* coeff = (const float*)d_in[2];
  const float* grid = (const float*)d_in[3];
  float* out = (float*)d_out;

  unsigned short* Acat = (unsigned short*)d_ws;              // 37.75 MB
  unsigned short* Wcat = Acat + (size_t)BATCH * KTOT;        // 18.87 MB
  unsigned short* Part = Wcat + (size_t)OUTF * KTOT;         // 33.55 MB

  build_w_kernel<<<OUTF * (KTOT / 8) / 256, 256, 0, stream>>>(bw, coeff, Wcat);
  build_a_kernel<<<BATCH * INF / 256, 256, 0, stream>>>(x, grid, Acat);
  gemm_kernel<<<SK * MTT * NTT, 512, 0, stream>>>(Acat, Wcat, Part);
  reduce_kernel<<<(int)(CSLAB / 8 / 256), 256, 0, stream>>>(Part, out);
}